// Round 3
// baseline (409.435 us; speedup 1.0000x reference)
//
#include <hip/hip_runtime.h>
#include <hip/hip_bf16.h>
#include <cstdint>

#define FDIM 128
#define ALPHA 0.2f
#define LN_EPS 1e-5f

typedef short v8s __attribute__((ext_vector_type(8)));
typedef float v4f __attribute__((ext_vector_type(4)));

__device__ __forceinline__ float bf2f(unsigned short u) {
  union { unsigned int i; float f; } c; c.i = ((unsigned int)u) << 16; return c.f;
}
__device__ __forceinline__ unsigned short f2bf(float f) {
  __hip_bfloat16 b = __float2bfloat16(f);
  return *reinterpret_cast<unsigned short*>(&b);
}
__device__ __forceinline__ float lo_bf(unsigned int g) {
  union { unsigned int i; float f; } c; c.i = g << 16; return c.f;
}
__device__ __forceinline__ float hi_bf(unsigned int g) {
  union { unsigned int i; float f; } c; c.i = g & 0xffff0000u; return c.f;
}

// ---- runtime dtype detection -----------------------------------------------
// fp32 data read as bf16 pairs: low halfword's bf16-exponent is ~uniform.
// bf16 data: low halfword IS a bf16 value ~N(0,1) -> exponent in [107,147].
// Whole wave must call (uses ballot). Returns 1 if x is fp32.
__device__ __forceinline__ int detect_f32(const unsigned int* __restrict__ xu) {
  int lane = threadIdx.x & 63;
  unsigned int u = xu[lane];
  int e = (u >> 7) & 0xff;
  bool inband = (e >= 107 && e <= 147);
  unsigned long long b = __ballot(inband);
  return (__popcll(b) < 48) ? 1 : 0;
}
// int64 edges: high words of first entries are zero (indices < 2^31).
__device__ __forceinline__ int detect_i64(const int* __restrict__ edge) {
  return ((edge[1] | edge[3] | edge[5] | edge[7]) == 0) ? 1 : 0;
}

__device__ __forceinline__ void load_edge(const int* __restrict__ edge, int e,
                                          int E, int i64, int N, int& s, int& d) {
  int sv, dv;
  if (i64) { sv = edge[2 * e]; dv = edge[2 * (E + e)]; }
  else     { sv = edge[e];     dv = edge[E + e]; }
  sv = sv < 0 ? 0 : (sv >= N ? N - 1 : sv);
  dv = dv < 0 ? 0 : (dv >= N ? N - 1 : dv);
  s = sv; d = dv;
}

// ---------------- K0: Wt[f][k] (bf16), a/bias/gamma/beta -> fp32 ------------
__global__ __launch_bounds__(256) void k_prep(
    const void* __restrict__ xv, const void* __restrict__ Wv,
    const void* __restrict__ av, const void* __restrict__ biasv,
    const void* __restrict__ gammav, const void* __restrict__ betav,
    unsigned short* __restrict__ Wt, float* __restrict__ aSf,
    float* __restrict__ aDf, float* __restrict__ biasf,
    float* __restrict__ gammaf, float* __restrict__ betaf) {
  int f32 = detect_f32((const unsigned int*)xv);
  int i = blockIdx.x * 256 + threadIdx.x;  // 64 blocks * 256 = 16384
  int k = i >> 7, f = i & 127;
  if (f32) Wt[f * FDIM + k] = f2bf(((const float*)Wv)[i]);
  else     Wt[f * FDIM + k] = ((const unsigned short*)Wv)[i];
  if (blockIdx.x == 0 && threadIdx.x < FDIM) {
    int t = threadIdx.x;
    if (f32) {
      aSf[t] = ((const float*)av)[t];
      aDf[t] = ((const float*)av)[FDIM + t];
      biasf[t] = ((const float*)biasv)[t];
      gammaf[t] = ((const float*)gammav)[t];
      betaf[t] = ((const float*)betav)[t];
    } else {
      aSf[t] = bf2f(((const unsigned short*)av)[t]);
      aDf[t] = bf2f(((const unsigned short*)av)[FDIM + t]);
      biasf[t] = bf2f(((const unsigned short*)biasv)[t]);
      gammaf[t] = bf2f(((const unsigned short*)gammav)[t]);
      betaf[t] = bf2f(((const unsigned short*)betav)[t]);
    }
  }
}

// ---------------- K1: h = x@W + bias (bf16 out), fused s_src/s_dst ----------
__global__ __launch_bounds__(256) void k_gemm(
    const void* __restrict__ xv, const unsigned short* __restrict__ wt,
    const float* __restrict__ biasf, const float* __restrict__ aSf,
    const float* __restrict__ aDf, unsigned short* __restrict__ hout,
    float* __restrict__ s_src, float* __restrict__ s_dst, int N) {
  __shared__ __align__(16) unsigned short xs[64 * 136];
  __shared__ __align__(16) unsigned short ws[128 * 136];
  int f32 = detect_f32((const unsigned int*)xv);
  int t = threadIdx.x;
  int node0 = blockIdx.x * 64;

#pragma unroll
  for (int i = 0; i < 8; ++i) {
    int c = t + 256 * i;
    int row = c >> 4, col = (c & 15) * 8;
    uint4 v = *(const uint4*)(wt + row * FDIM + col);
    *(uint4*)(ws + row * 136 + col) = v;
  }
  if (f32) {
    const float* xf = (const float*)xv;
#pragma unroll
    for (int i = 0; i < 4; ++i) {
      int c = t + 256 * i;
      int row = c >> 4, col = (c & 15) * 8;
      int r2 = node0 + row;
      int rc = r2 < N ? r2 : N - 1;
      float4 v0 = *(const float4*)(xf + (size_t)rc * FDIM + col);
      float4 v1 = *(const float4*)(xf + (size_t)rc * FDIM + col + 4);
      ushort4 p0, p1;
      p0.x = f2bf(v0.x); p0.y = f2bf(v0.y); p0.z = f2bf(v0.z); p0.w = f2bf(v0.w);
      p1.x = f2bf(v1.x); p1.y = f2bf(v1.y); p1.z = f2bf(v1.z); p1.w = f2bf(v1.w);
      *(ushort4*)(xs + row * 136 + col) = p0;
      *(ushort4*)(xs + row * 136 + col + 4) = p1;
    }
  } else {
    const unsigned short* xb = (const unsigned short*)xv;
#pragma unroll
    for (int i = 0; i < 4; ++i) {
      int c = t + 256 * i;
      int row = c >> 4, col = (c & 15) * 8;
      int r2 = node0 + row;
      int rc = r2 < N ? r2 : N - 1;
      uint4 v = *(const uint4*)(xb + (size_t)rc * FDIM + col);
      *(uint4*)(xs + row * 136 + col) = v;
    }
  }
  __syncthreads();

  int wave = t >> 6, lane = t & 63;
  int l16 = lane & 15, q = lane >> 4;

  v4f acc[8];
#pragma unroll
  for (int i = 0; i < 8; ++i) acc[i] = (v4f){0.f, 0.f, 0.f, 0.f};

#pragma unroll
  for (int ks = 0; ks < 4; ++ks) {
    int ko = ks * 32 + q * 8;
    v8s b = *(const v8s*)(xs + (wave * 16 + l16) * 136 + ko);
#pragma unroll
    for (int tt = 0; tt < 8; ++tt) {
      v8s afr = *(const v8s*)(ws + (tt * 16 + l16) * 136 + ko);
      acc[tt] = __builtin_amdgcn_mfma_f32_16x16x32_bf16(afr, b, acc[tt], 0, 0, 0);
    }
  }

  int node = node0 + wave * 16 + l16;
  bool valid = node < N;
  float ss = 0.f, sd = 0.f;
#pragma unroll
  for (int tt = 0; tt < 8; ++tt) {
    int f0 = tt * 16 + q * 4;
    float4 bi = *(const float4*)(biasf + f0);
    float4 as4 = *(const float4*)(aSf + f0);
    float4 ad4 = *(const float4*)(aDf + f0);
    float v0 = acc[tt][0] + bi.x;
    float v1 = acc[tt][1] + bi.y;
    float v2 = acc[tt][2] + bi.z;
    float v3 = acc[tt][3] + bi.w;
    ss += v0 * as4.x + v1 * as4.y + v2 * as4.z + v3 * as4.w;
    sd += v0 * ad4.x + v1 * ad4.y + v2 * ad4.z + v3 * ad4.w;
    if (valid) {
      ushort4 pk;
      pk.x = f2bf(v0); pk.y = f2bf(v1); pk.z = f2bf(v2); pk.w = f2bf(v3);
      *(ushort4*)(hout + (size_t)node * FDIM + f0) = pk;
    }
  }
  ss += __shfl_xor(ss, 16); ss += __shfl_xor(ss, 32);
  sd += __shfl_xor(sd, 16); sd += __shfl_xor(sd, 32);
  if (q == 0 && valid) { s_src[node] = ss; s_dst[node] = sd; }
}

// ---------------- K2: count degree + block max of leaky score ---------------
__global__ __launch_bounds__(256) void k_count(
    const int* __restrict__ edge, const float* __restrict__ ssrc,
    const float* __restrict__ sdst, int* __restrict__ counts,
    float* __restrict__ pmax, int E, int N) {
  int i64 = detect_i64(edge);
  int tid = blockIdx.x * 256 + threadIdx.x;
  int stride = gridDim.x * 256;
  float m = -1e30f;
  for (int e = tid; e < E; e += stride) {
    int s, d;
    load_edge(edge, e, E, i64, N, s, d);
    float sc = ssrc[s] + sdst[d];
    sc = sc > 0.f ? sc : ALPHA * sc;
    m = fmaxf(m, sc);
    atomicAdd(&counts[s], 1);
  }
#pragma unroll
  for (int o = 1; o < 64; o <<= 1) m = fmaxf(m, __shfl_xor(m, o));
  __shared__ float red[4];
  if ((threadIdx.x & 63) == 0) red[threadIdx.x >> 6] = m;
  __syncthreads();
  if (threadIdx.x == 0)
    pmax[blockIdx.x] = fmaxf(fmaxf(red[0], red[1]), fmaxf(red[2], red[3]));
}

__global__ __launch_bounds__(1024) void k_max(const float* __restrict__ pmax,
                                              float* __restrict__ Mp) {
  int t = threadIdx.x;
  float m = pmax[t];
#pragma unroll
  for (int o = 1; o < 64; o <<= 1) m = fmaxf(m, __shfl_xor(m, o));
  __shared__ float red[16];
  if ((t & 63) == 0) red[t >> 6] = m;
  __syncthreads();
  if (t == 0) {
    float r = red[0];
#pragma unroll
    for (int i = 1; i < 16; ++i) r = fmaxf(r, red[i]);
    *Mp = r;
  }
}

// ---------------- K3: 3-kernel exclusive scan of counts ---------------------
__global__ __launch_bounds__(256) void k_scan1(const int* __restrict__ counts,
                                               int* __restrict__ bsum, int N) {
  int i = blockIdx.x * 256 + threadIdx.x;
  int c = (i < N) ? counts[i] : 0;
#pragma unroll
  for (int o = 1; o < 64; o <<= 1) c += __shfl_xor(c, o);
  __shared__ int red[4];
  if ((threadIdx.x & 63) == 0) red[threadIdx.x >> 6] = c;
  __syncthreads();
  if (threadIdx.x == 0) bsum[blockIdx.x] = red[0] + red[1] + red[2] + red[3];
}

__global__ __launch_bounds__(512) void k_scan2(const int* __restrict__ bsum,
                                               int* __restrict__ boff, int NB,
                                               int* __restrict__ row_end, int E) {
  __shared__ int sd[512];
  int t = threadIdx.x;
  int v = (t < NB) ? bsum[t] : 0;
  sd[t] = v;
  __syncthreads();
  for (int off = 1; off < 512; off <<= 1) {
    int add = (t >= off) ? sd[t - off] : 0;
    __syncthreads();
    sd[t] += add;
    __syncthreads();
  }
  if (t < NB) boff[t] = sd[t] - v;
  if (t == 0) *row_end = E;  // row_start[N] = E
}

__global__ __launch_bounds__(256) void k_scan3(const int* __restrict__ counts,
                                               const int* __restrict__ boff,
                                               int* __restrict__ row_start,
                                               int* __restrict__ cursor, int N) {
  __shared__ int sd[256];
  int t = threadIdx.x;
  int i = blockIdx.x * 256 + t;
  int c = (i < N) ? counts[i] : 0;
  sd[t] = c;
  __syncthreads();
  for (int off = 1; off < 256; off <<= 1) {
    int add = (t >= off) ? sd[t - off] : 0;
    __syncthreads();
    sd[t] += add;
    __syncthreads();
  }
  if (i < N) {
    int v = boff[blockIdx.x] + sd[t] - c;
    row_start[i] = v;
    cursor[i] = v;
  }
}

// ---------------- K4: scatter dst into CSR ----------------------------------
__global__ __launch_bounds__(256) void k_scatter(
    const int* __restrict__ edge, int* __restrict__ cursor,
    int* __restrict__ epd, int E, int N) {
  int i64 = detect_i64(edge);
  int tid = blockIdx.x * 256 + threadIdx.x;
  int stride = gridDim.x * 256;
  for (int e = tid; e < E; e += stride) {
    int s, d;
    load_edge(edge, e, E, i64, N, s, d);
    int pos = atomicAdd(&cursor[s], 1);
    pos = pos < 0 ? 0 : (pos >= E ? E - 1 : pos);
    epd[pos] = d;
  }
}

// ---------------- K5: aggregate + residual + LayerNorm + ELU ----------------
// one wave per row; lane handles features 2*lane, 2*lane+1
__global__ __launch_bounds__(256) void k_agg(
    const void* __restrict__ xv, const unsigned short* __restrict__ h,
    const int* __restrict__ row_start, const int* __restrict__ epd,
    const float* __restrict__ ssrc, const float* __restrict__ sdst,
    const float* __restrict__ Mp, const float* __restrict__ gammaf,
    const float* __restrict__ betaf, void* __restrict__ outv, int N) {
  int f32 = detect_f32((const unsigned int*)xv);
  int wave = threadIdx.x >> 6, lane = threadIdx.x & 63;
  int row = blockIdx.x * 4 + wave;
  if (row >= N) return;
  float M = *Mp;
  float srow = ssrc[row];
  int b0 = row_start[row], b1 = row_start[row + 1];
  float ax = 0.f, ay = 0.f, rs = 0.f;
  int j = b0;
  for (; j + 4 <= b1; j += 4) {
    int d0 = epd[j], d1 = epd[j + 1], d2 = epd[j + 2], d3 = epd[j + 3];
    unsigned int g0 = *(const unsigned int*)(h + (size_t)d0 * FDIM + lane * 2);
    unsigned int g1 = *(const unsigned int*)(h + (size_t)d1 * FDIM + lane * 2);
    unsigned int g2 = *(const unsigned int*)(h + (size_t)d2 * FDIM + lane * 2);
    unsigned int g3 = *(const unsigned int*)(h + (size_t)d3 * FDIM + lane * 2);
    float s0 = srow + sdst[d0], s1 = srow + sdst[d1];
    float s2 = srow + sdst[d2], s3 = srow + sdst[d3];
    s0 = s0 > 0.f ? s0 : ALPHA * s0; s1 = s1 > 0.f ? s1 : ALPHA * s1;
    s2 = s2 > 0.f ? s2 : ALPHA * s2; s3 = s3 > 0.f ? s3 : ALPHA * s3;
    float w0 = __expf(s0 - M), w1 = __expf(s1 - M);
    float w2 = __expf(s2 - M), w3 = __expf(s3 - M);
    rs += (w0 + w1) + (w2 + w3);
    ax += w0 * lo_bf(g0) + w1 * lo_bf(g1) + w2 * lo_bf(g2) + w3 * lo_bf(g3);
    ay += w0 * hi_bf(g0) + w1 * hi_bf(g1) + w2 * hi_bf(g2) + w3 * hi_bf(g3);
  }
  for (; j < b1; ++j) {
    int d = epd[j];
    unsigned int g = *(const unsigned int*)(h + (size_t)d * FDIM + lane * 2);
    float sc = srow + sdst[d];
    sc = sc > 0.f ? sc : ALPHA * sc;
    float w = __expf(sc - M);
    rs += w;
    ax += w * lo_bf(g);
    ay += w * hi_bf(g);
  }
  float inv = 1.0f / (rs + 1e-8f);
  float xlo, xhi;
  if (f32) {
    float2 xr = *(const float2*)((const float*)xv + (size_t)row * FDIM + lane * 2);
    xlo = xr.x; xhi = xr.y;
  } else {
    unsigned int xr = *(const unsigned int*)((const unsigned short*)xv +
                                             (size_t)row * FDIM + lane * 2);
    xlo = lo_bf(xr); xhi = hi_bf(xr);
  }
  float vx = ax * inv + xlo;
  float vy = ay * inv + xhi;
  float sum = vx + vy, sq = vx * vx + vy * vy;
#pragma unroll
  for (int o = 1; o < 64; o <<= 1) {
    sum += __shfl_xor(sum, o);
    sq += __shfl_xor(sq, o);
  }
  float mean = sum * (1.f / FDIM);
  float var = sq * (1.f / FDIM) - mean * mean;
  var = fmaxf(var, 0.f);
  float rstd = rsqrtf(var + LN_EPS);
  float2 gb = *(const float2*)(gammaf + lane * 2);
  float2 bb = *(const float2*)(betaf + lane * 2);
  float y0 = (vx - mean) * rstd * gb.x + bb.x;
  float y1 = (vy - mean) * rstd * gb.y + bb.y;
  y0 = y0 > 0.f ? y0 : expm1f(y0);
  y1 = y1 > 0.f ? y1 : expm1f(y1);
  if (f32) {
    float2 o2; o2.x = y0; o2.y = y1;
    *(float2*)((float*)outv + (size_t)row * FDIM + lane * 2) = o2;
  } else {
    unsigned int o01 = (unsigned int)f2bf(y0) | ((unsigned int)f2bf(y1) << 16);
    *(unsigned int*)((unsigned short*)outv + (size_t)row * FDIM + lane * 2) = o01;
  }
}

extern "C" void kernel_launch(void* const* d_in, const int* in_sizes, int n_in,
                              void* d_out, int out_size, void* d_ws, size_t ws_size,
                              hipStream_t stream) {
  const void* x = d_in[0];
  const int* edge = (const int*)d_in[1];
  const void* W = d_in[2];
  const void* a = d_in[3];
  const void* bias = d_in[4];
  const void* gamma = d_in[5];
  const void* beta = d_in[6];
  int N = in_sizes[0] / FDIM;
  int E = in_sizes[1] / 2;
  int NB = (N + 255) / 256;  // 391 for N=100000; must be <= 512 for k_scan2

  char* p = (char*)d_ws;
  auto alloc = [&](size_t bytes) {
    char* r = p;
    p += (bytes + 255) & ~(size_t)255;
    return r;
  };
  unsigned short* Wt = (unsigned short*)alloc((size_t)FDIM * FDIM * 2);
  float* aSf = (float*)alloc(FDIM * 4);
  float* aDf = (float*)alloc(FDIM * 4);
  float* biasf = (float*)alloc(FDIM * 4);
  float* gammaf = (float*)alloc(FDIM * 4);
  float* betaf = (float*)alloc(FDIM * 4);
  unsigned short* h = (unsigned short*)alloc((size_t)N * FDIM * 2);
  float* ssrc = (float*)alloc((size_t)N * 4);
  float* sdst = (float*)alloc((size_t)N * 4);
  int* counts = (int*)alloc((size_t)N * 4);
  int* rowst = (int*)alloc(((size_t)N + 1) * 4);
  int* cursor = (int*)alloc((size_t)N * 4);
  int* bsum = (int*)alloc((size_t)NB * 4);
  int* boff = (int*)alloc((size_t)NB * 4);
  int* epd = (int*)alloc((size_t)E * 4);
  float* pmax = (float*)alloc(1024 * 4);
  float* Mp = (float*)alloc(256);

  hipMemsetAsync(counts, 0, (size_t)N * 4, stream);
  k_prep<<<64, 256, 0, stream>>>(x, W, a, bias, gamma, beta, Wt, aSf, aDf,
                                 biasf, gammaf, betaf);
  k_gemm<<<(N + 63) / 64, 256, 0, stream>>>(x, Wt, biasf, aSf, aDf, h, ssrc,
                                            sdst, N);
  k_count<<<1024, 256, 0, stream>>>(edge, ssrc, sdst, counts, pmax, E, N);
  k_max<<<1, 1024, 0, stream>>>(pmax, Mp);
  k_scan1<<<NB, 256, 0, stream>>>(counts, bsum, N);
  k_scan2<<<1, 512, 0, stream>>>(bsum, boff, NB, rowst + N, E);
  k_scan3<<<NB, 256, 0, stream>>>(counts, boff, rowst, cursor, N);
  k_scatter<<<1024, 256, 0, stream>>>(edge, cursor, epd, E, N);
  k_agg<<<(N + 3) / 4, 256, 0, stream>>>(x, h, rowst, epd, ssrc, sdst, Mp,
                                         gammaf, betaf, d_out, N);
}

// Round 4
// 374.305 us; speedup vs baseline: 1.0939x; 1.0939x over previous
//
#include <hip/hip_runtime.h>
#include <hip/hip_bf16.h>
#include <cstdint>

#define FDIM 128
#define ALPHA 0.2f
#define LN_EPS 1e-5f
#define SHIFT 7           // 128 nodes per bucket
#define NBLK 256          // writer blocks for binning passes
#define CAP 3072          // max edges staged per bucket in LDS (mean ~2046)

typedef short v8s __attribute__((ext_vector_type(8)));
typedef float v4f __attribute__((ext_vector_type(4)));

__device__ __forceinline__ float bf2f(unsigned short u) {
  union { unsigned int i; float f; } c; c.i = ((unsigned int)u) << 16; return c.f;
}
__device__ __forceinline__ unsigned short f2bf(float f) {
  __hip_bfloat16 b = __float2bfloat16(f);
  return *reinterpret_cast<unsigned short*>(&b);
}
__device__ __forceinline__ float lo_bf(unsigned int g) {
  union { unsigned int i; float f; } c; c.i = g << 16; return c.f;
}
__device__ __forceinline__ float hi_bf(unsigned int g) {
  union { unsigned int i; float f; } c; c.i = g & 0xffff0000u; return c.f;
}

// fp32 data read as bf16 pairs: low halfword's bf16-exponent ~uniform.
// bf16 N(0,1) data: exponent in [107,147]. Wave-uniform result.
__device__ __forceinline__ int detect_f32(const unsigned int* __restrict__ xu) {
  int lane = threadIdx.x & 63;
  unsigned int u = xu[lane];
  int e = (u >> 7) & 0xff;
  bool inband = (e >= 107 && e <= 147);
  unsigned long long b = __ballot(inband);
  return (__popcll(b) < 48) ? 1 : 0;
}
__device__ __forceinline__ int detect_i64(const int* __restrict__ edge) {
  return ((edge[1] | edge[3] | edge[5] | edge[7]) == 0) ? 1 : 0;
}

__device__ __forceinline__ void load_edge(const int* __restrict__ edge, int e,
                                          int E, int i64, int N, int& s, int& d) {
  int sv, dv;
  if (i64) { sv = edge[2 * e]; dv = edge[2 * (E + e)]; }
  else     { sv = edge[e];     dv = edge[E + e]; }
  sv = sv < 0 ? 0 : (sv >= N ? N - 1 : sv);
  dv = dv < 0 ? 0 : (dv >= N ? N - 1 : dv);
  s = sv; d = dv;
}

// ---------------- K0: Wt[f][k] (bf16), a/bias/gamma/beta -> fp32 ------------
__global__ __launch_bounds__(256) void k_prep(
    const void* __restrict__ xv, const void* __restrict__ Wv,
    const void* __restrict__ av, const void* __restrict__ biasv,
    const void* __restrict__ gammav, const void* __restrict__ betav,
    unsigned short* __restrict__ Wt, float* __restrict__ aSf,
    float* __restrict__ aDf, float* __restrict__ biasf,
    float* __restrict__ gammaf, float* __restrict__ betaf) {
  int f32 = detect_f32((const unsigned int*)xv);
  int i = blockIdx.x * 256 + threadIdx.x;
  int k = i >> 7, f = i & 127;
  if (f32) Wt[f * FDIM + k] = f2bf(((const float*)Wv)[i]);
  else     Wt[f * FDIM + k] = ((const unsigned short*)Wv)[i];
  if (blockIdx.x == 0 && threadIdx.x < FDIM) {
    int t = threadIdx.x;
    if (f32) {
      aSf[t] = ((const float*)av)[t];
      aDf[t] = ((const float*)av)[FDIM + t];
      biasf[t] = ((const float*)biasv)[t];
      gammaf[t] = ((const float*)gammav)[t];
      betaf[t] = ((const float*)betav)[t];
    } else {
      aSf[t] = bf2f(((const unsigned short*)av)[t]);
      aDf[t] = bf2f(((const unsigned short*)av)[FDIM + t]);
      biasf[t] = bf2f(((const unsigned short*)biasv)[t]);
      gammaf[t] = bf2f(((const unsigned short*)gammav)[t]);
      betaf[t] = bf2f(((const unsigned short*)betav)[t]);
    }
  }
}

// ---------------- K1: h = x@W + bias (bf16 out), fused s_src/s_dst ----------
__global__ __launch_bounds__(256) void k_gemm(
    const void* __restrict__ xv, const unsigned short* __restrict__ wt,
    const float* __restrict__ biasf, const float* __restrict__ aSf,
    const float* __restrict__ aDf, unsigned short* __restrict__ hout,
    float* __restrict__ s_src, float* __restrict__ s_dst, int N) {
  __shared__ __align__(16) unsigned short xs[64 * 136];
  __shared__ __align__(16) unsigned short ws[128 * 136];
  int f32 = detect_f32((const unsigned int*)xv);
  int t = threadIdx.x;
  int node0 = blockIdx.x * 64;

#pragma unroll
  for (int i = 0; i < 8; ++i) {
    int c = t + 256 * i;
    int row = c >> 4, col = (c & 15) * 8;
    uint4 v = *(const uint4*)(wt + row * FDIM + col);
    *(uint4*)(ws + row * 136 + col) = v;
  }
  if (f32) {
    const float* xf = (const float*)xv;
#pragma unroll
    for (int i = 0; i < 4; ++i) {
      int c = t + 256 * i;
      int row = c >> 4, col = (c & 15) * 8;
      int r2 = node0 + row;
      int rc = r2 < N ? r2 : N - 1;
      float4 v0 = *(const float4*)(xf + (size_t)rc * FDIM + col);
      float4 v1 = *(const float4*)(xf + (size_t)rc * FDIM + col + 4);
      ushort4 p0, p1;
      p0.x = f2bf(v0.x); p0.y = f2bf(v0.y); p0.z = f2bf(v0.z); p0.w = f2bf(v0.w);
      p1.x = f2bf(v1.x); p1.y = f2bf(v1.y); p1.z = f2bf(v1.z); p1.w = f2bf(v1.w);
      *(ushort4*)(xs + row * 136 + col) = p0;
      *(ushort4*)(xs + row * 136 + col + 4) = p1;
    }
  } else {
    const unsigned short* xb = (const unsigned short*)xv;
#pragma unroll
    for (int i = 0; i < 4; ++i) {
      int c = t + 256 * i;
      int row = c >> 4, col = (c & 15) * 8;
      int r2 = node0 + row;
      int rc = r2 < N ? r2 : N - 1;
      uint4 v = *(const uint4*)(xb + (size_t)rc * FDIM + col);
      *(uint4*)(xs + row * 136 + col) = v;
    }
  }
  __syncthreads();

  int wave = t >> 6, lane = t & 63;
  int l16 = lane & 15, q = lane >> 4;

  v4f acc[8];
#pragma unroll
  for (int i = 0; i < 8; ++i) acc[i] = (v4f){0.f, 0.f, 0.f, 0.f};

#pragma unroll
  for (int ks = 0; ks < 4; ++ks) {
    int ko = ks * 32 + q * 8;
    v8s b = *(const v8s*)(xs + (wave * 16 + l16) * 136 + ko);
#pragma unroll
    for (int tt = 0; tt < 8; ++tt) {
      v8s afr = *(const v8s*)(ws + (tt * 16 + l16) * 136 + ko);
      acc[tt] = __builtin_amdgcn_mfma_f32_16x16x32_bf16(afr, b, acc[tt], 0, 0, 0);
    }
  }

  int node = node0 + wave * 16 + l16;
  bool valid = node < N;
  float ss = 0.f, sd = 0.f;
#pragma unroll
  for (int tt = 0; tt < 8; ++tt) {
    int f0 = tt * 16 + q * 4;
    float4 bi = *(const float4*)(biasf + f0);
    float4 as4 = *(const float4*)(aSf + f0);
    float4 ad4 = *(const float4*)(aDf + f0);
    float v0 = acc[tt][0] + bi.x;
    float v1 = acc[tt][1] + bi.y;
    float v2 = acc[tt][2] + bi.z;
    float v3 = acc[tt][3] + bi.w;
    ss += v0 * as4.x + v1 * as4.y + v2 * as4.z + v3 * as4.w;
    sd += v0 * ad4.x + v1 * ad4.y + v2 * ad4.z + v3 * ad4.w;
    if (valid) {
      ushort4 pk;
      pk.x = f2bf(v0); pk.y = f2bf(v1); pk.z = f2bf(v2); pk.w = f2bf(v3);
      *(ushort4*)(hout + (size_t)node * FDIM + f0) = pk;
    }
  }
  ss += __shfl_xor(ss, 16); ss += __shfl_xor(ss, 32);
  sd += __shfl_xor(sd, 16); sd += __shfl_xor(sd, 32);
  if (q == 0 && valid) { s_src[node] = ss; s_dst[node] = sd; }
}

// ---------------- K2: per-block bucket histogram (no global atomics) --------
__global__ __launch_bounds__(256) void k_binA(
    const int* __restrict__ edge, int* __restrict__ cnt, int E, int N,
    int NBUCK, int chunk) {
  __shared__ int lcnt[1024];
  int t = threadIdx.x, k = blockIdx.x;
  for (int i = t; i < NBUCK; i += 256) lcnt[i] = 0;
  __syncthreads();
  int i64 = detect_i64(edge);
  int e0 = k * chunk, e1 = min(E, e0 + chunk);
  for (int e = e0 + t; e < e1; e += 256) {
    int s, d;
    load_edge(edge, e, E, i64, N, s, d);
    atomicAdd(&lcnt[s >> SHIFT], 1);
  }
  __syncthreads();
  for (int i = t; i < NBUCK; i += 256) cnt[k * NBUCK + i] = lcnt[i];
}

// column scan: block b scans cnt[0..NBLK)[b] -> coff (exclusive), btot
__global__ __launch_bounds__(256) void k_scanB1(
    const int* __restrict__ cnt, int* __restrict__ coff,
    int* __restrict__ btot, int NBUCK) {
  __shared__ int sd[256];
  int t = threadIdx.x, b = blockIdx.x;
  int v = cnt[t * NBUCK + b];
  sd[t] = v;
  __syncthreads();
  for (int off = 1; off < 256; off <<= 1) {
    int add = (t >= off) ? sd[t - off] : 0;
    __syncthreads();
    sd[t] += add;
    __syncthreads();
  }
  coff[t * NBUCK + b] = sd[t] - v;
  if (t == 255) btot[b] = sd[255];
}

__global__ __launch_bounds__(1024) void k_scanB2(
    const int* __restrict__ btot, int* __restrict__ bbase, int NBUCK) {
  __shared__ int sd[1024];
  int t = threadIdx.x;
  int v = (t < NBUCK) ? btot[t] : 0;
  sd[t] = v;
  __syncthreads();
  for (int off = 1; off < 1024; off <<= 1) {
    int add = (t >= off) ? sd[t - off] : 0;
    __syncthreads();
    sd[t] += add;
    __syncthreads();
  }
  if (t < NBUCK) bbase[t] = sd[t] - v;
}

// ---------------- K3: deterministic binned scatter (LDS cursors only) -------
__global__ __launch_bounds__(256) void k_binB(
    const int* __restrict__ edge, const int* __restrict__ coff,
    const int* __restrict__ bbase, uint2* __restrict__ binned, int E, int N,
    int NBUCK, int chunk) {
  __shared__ int lcur[1024];
  int t = threadIdx.x, k = blockIdx.x;
  for (int i = t; i < NBUCK; i += 256) lcur[i] = bbase[i] + coff[k * NBUCK + i];
  __syncthreads();
  int i64 = detect_i64(edge);
  int e0 = k * chunk, e1 = min(E, e0 + chunk);
  for (int e = e0 + t; e < e1; e += 256) {
    int s, d;
    load_edge(edge, e, E, i64, N, s, d);
    int pos = atomicAdd(&lcur[s >> SHIFT], 1);
    uint2 pk; pk.x = (unsigned int)s; pk.y = (unsigned int)d;
    binned[pos] = pk;
  }
}

// ---------------- shared epilogue: rescale+residual+LN+ELU+store ------------
__device__ __forceinline__ void ln_elu_store(
    int row, int lane, float ax, float ay, float rs, const void* __restrict__ xv,
    int f32, const float* __restrict__ gammaf, const float* __restrict__ betaf,
    void* __restrict__ outv) {
  float inv = 1.0f / (rs + 1e-8f);
  float xlo, xhi;
  if (f32) {
    float2 xr = *(const float2*)((const float*)xv + (size_t)row * FDIM + lane * 2);
    xlo = xr.x; xhi = xr.y;
  } else {
    unsigned int xr = *(const unsigned int*)((const unsigned short*)xv +
                                             (size_t)row * FDIM + lane * 2);
    xlo = lo_bf(xr); xhi = hi_bf(xr);
  }
  float vx = ax * inv + xlo;
  float vy = ay * inv + xhi;
  float sum = vx + vy, sq = vx * vx + vy * vy;
#pragma unroll
  for (int o = 1; o < 64; o <<= 1) {
    sum += __shfl_xor(sum, o);
    sq += __shfl_xor(sq, o);
  }
  float mean = sum * (1.f / FDIM);
  float var = sq * (1.f / FDIM) - mean * mean;
  var = fmaxf(var, 0.f);
  float rstd = rsqrtf(var + LN_EPS);
  float2 gb = *(const float2*)(gammaf + lane * 2);
  float2 bb = *(const float2*)(betaf + lane * 2);
  float y0 = (vx - mean) * rstd * gb.x + bb.x;
  float y1 = (vy - mean) * rstd * gb.y + bb.y;
  y0 = y0 > 0.f ? y0 : expm1f(y0);
  y1 = y1 > 0.f ? y1 : expm1f(y1);
  if (f32) {
    float2 o2; o2.x = y0; o2.y = y1;
    *(float2*)((float*)outv + (size_t)row * FDIM + lane * 2) = o2;
  } else {
    unsigned int o01 = (unsigned int)f2bf(y0) | ((unsigned int)f2bf(y1) << 16);
    *(unsigned int*)((unsigned short*)outv + (size_t)row * FDIM + lane * 2) = o01;
  }
}

// ---------------- K4: fused LDS-CSR build + aggregate + LN + ELU ------------
// one block per bucket (128 rows); wave per row
__global__ __launch_bounds__(256) void k_agg(
    const void* __restrict__ xv, const unsigned short* __restrict__ h,
    const uint2* __restrict__ binned, const int* __restrict__ bbase,
    const int* __restrict__ btot, const float* __restrict__ ssrc,
    const float* __restrict__ sdst, const float* __restrict__ gammaf,
    const float* __restrict__ betaf, void* __restrict__ outv, int N) {
  __shared__ uint2 prs[CAP];
  __shared__ uint2 csr[CAP];  // x = dst, y = bits(w)
  __shared__ int lcnt[128], rst[128], lcur[128];
  int t = threadIdx.x;
  int b = blockIdx.x;
  int base = bbase[b], tot = btot[b];
  int r0 = b << SHIFT;
  int nrows = min(128, N - r0);
  int f32 = detect_f32((const unsigned int*)xv);
  int wave = t >> 6, lane = t & 63;

  bool staged = (tot <= CAP);
  if (staged) {
    for (int i = t; i < tot; i += 256) prs[i] = binned[base + i];
  }
  if (t < 128) lcnt[t] = 0;
  __syncthreads();

  if (staged) {
    for (int i = t; i < tot; i += 256) atomicAdd(&lcnt[prs[i].x - r0], 1);
  } else {
    for (int i = t; i < tot; i += 256) atomicAdd(&lcnt[binned[base + i].x - r0], 1);
  }
  __syncthreads();
  if (t < 128) rst[t] = lcnt[t];
  __syncthreads();
  for (int off = 1; off < 128; off <<= 1) {
    int add = (t >= off && t < 128) ? rst[t - off] : 0;
    __syncthreads();
    if (t < 128) rst[t] += add;
    __syncthreads();
  }
  if (t < 128) lcur[t] = rst[t] - lcnt[t];
  __syncthreads();

  if (staged) {
    for (int i = t; i < tot; i += 256) {
      uint2 p = prs[i];
      float sc = ssrc[p.x] + sdst[p.y];
      sc = sc > 0.f ? sc : ALPHA * sc;
      float w = __expf(sc);
      int pos = atomicAdd(&lcur[p.x - r0], 1);
      uint2 cw; cw.x = p.y; cw.y = __float_as_uint(w);
      csr[pos] = cw;
    }
    __syncthreads();

    for (int r = wave; r < nrows; r += 4) {
      int row = r0 + r;
      int b1 = rst[r], b0 = b1 - lcnt[r];
      float ax = 0.f, ay = 0.f, rs = 0.f;
      int j = b0;
      for (; j + 4 <= b1; j += 4) {
        uint2 c0 = csr[j], c1 = csr[j + 1], c2 = csr[j + 2], c3 = csr[j + 3];
        unsigned int g0 = *(const unsigned int*)(h + (size_t)c0.x * FDIM + lane * 2);
        unsigned int g1 = *(const unsigned int*)(h + (size_t)c1.x * FDIM + lane * 2);
        unsigned int g2 = *(const unsigned int*)(h + (size_t)c2.x * FDIM + lane * 2);
        unsigned int g3 = *(const unsigned int*)(h + (size_t)c3.x * FDIM + lane * 2);
        float w0 = __uint_as_float(c0.y), w1 = __uint_as_float(c1.y);
        float w2 = __uint_as_float(c2.y), w3 = __uint_as_float(c3.y);
        rs += (w0 + w1) + (w2 + w3);
        ax += w0 * lo_bf(g0) + w1 * lo_bf(g1) + w2 * lo_bf(g2) + w3 * lo_bf(g3);
        ay += w0 * hi_bf(g0) + w1 * hi_bf(g1) + w2 * hi_bf(g2) + w3 * hi_bf(g3);
      }
      for (; j < b1; ++j) {
        uint2 c = csr[j];
        unsigned int g = *(const unsigned int*)(h + (size_t)c.x * FDIM + lane * 2);
        float w = __uint_as_float(c.y);
        rs += w;
        ax += w * lo_bf(g);
        ay += w * hi_bf(g);
      }
      ln_elu_store(row, lane, ax, ay, rs, xv, f32, gammaf, betaf, outv);
    }
  } else {
    // statistically-unreachable fallback (bucket > CAP edges): scan-all
    for (int r = wave; r < nrows; r += 4) {
      int row = r0 + r;
      float ax = 0.f, ay = 0.f, rs = 0.f;
      for (int j = 0; j < tot; ++j) {
        uint2 p = binned[base + j];
        if ((int)p.x == row) {
          float sc = ssrc[p.x] + sdst[p.y];
          sc = sc > 0.f ? sc : ALPHA * sc;
          float w = __expf(sc);
          unsigned int g = *(const unsigned int*)(h + (size_t)p.y * FDIM + lane * 2);
          rs += w;
          ax += w * lo_bf(g);
          ay += w * hi_bf(g);
        }
      }
      ln_elu_store(row, lane, ax, ay, rs, xv, f32, gammaf, betaf, outv);
    }
  }
}

extern "C" void kernel_launch(void* const* d_in, const int* in_sizes, int n_in,
                              void* d_out, int out_size, void* d_ws, size_t ws_size,
                              hipStream_t stream) {
  const void* x = d_in[0];
  const int* edge = (const int*)d_in[1];
  const void* W = d_in[2];
  const void* a = d_in[3];
  const void* bias = d_in[4];
  const void* gamma = d_in[5];
  const void* beta = d_in[6];
  int N = in_sizes[0] / FDIM;
  int E = in_sizes[1] / 2;
  int NBUCK = (N + 127) >> SHIFT;       // 782 for N=100000 (must be <= 1024)
  int chunk = (E + NBLK - 1) / NBLK;    // edges per writer block

  char* p = (char*)d_ws;
  auto alloc = [&](size_t bytes) {
    char* r = p;
    p += (bytes + 255) & ~(size_t)255;
    return r;
  };
  unsigned short* Wt = (unsigned short*)alloc((size_t)FDIM * FDIM * 2);
  float* aSf = (float*)alloc(FDIM * 4);
  float* aDf = (float*)alloc(FDIM * 4);
  float* biasf = (float*)alloc(FDIM * 4);
  float* gammaf = (float*)alloc(FDIM * 4);
  float* betaf = (float*)alloc(FDIM * 4);
  unsigned short* h = (unsigned short*)alloc((size_t)N * FDIM * 2);
  float* ssrc = (float*)alloc((size_t)N * 4);
  float* sdst = (float*)alloc((size_t)N * 4);
  int* cnt = (int*)alloc((size_t)NBLK * NBUCK * 4);
  int* coff = (int*)alloc((size_t)NBLK * NBUCK * 4);
  int* btot = (int*)alloc((size_t)NBUCK * 4);
  int* bbase = (int*)alloc((size_t)NBUCK * 4);
  uint2* binned = (uint2*)alloc((size_t)E * 8);

  k_prep<<<64, 256, 0, stream>>>(x, W, a, bias, gamma, beta, Wt, aSf, aDf,
                                 biasf, gammaf, betaf);
  k_gemm<<<(N + 63) / 64, 256, 0, stream>>>(x, Wt, biasf, aSf, aDf, h, ssrc,
                                            sdst, N);
  k_binA<<<NBLK, 256, 0, stream>>>(edge, cnt, E, N, NBUCK, chunk);
  k_scanB1<<<NBUCK, 256, 0, stream>>>(cnt, coff, btot, NBUCK);
  k_scanB2<<<1, 1024, 0, stream>>>(btot, bbase, NBUCK);
  k_binB<<<NBLK, 256, 0, stream>>>(edge, coff, bbase, binned, E, N, NBUCK, chunk);
  k_agg<<<NBUCK, 256, 0, stream>>>(x, h, binned, bbase, btot, ssrc, sdst,
                                   gammaf, betaf, d_out, N);
}